// Round 6
// baseline (109.736 us; speedup 1.0000x reference)
//
#include <hip/hip_runtime.h>
#include <math.h>

#define S 4096
#define EPS 1e-5f

#if __has_builtin(__builtin_amdgcn_exp2f)
#define EXP2F(x) __builtin_amdgcn_exp2f(x)
#else
#define EXP2F(x) exp2f(x)
#endif

// ws float-index offsets
#define WS_PSUM 0            // [64]
#define WS_PSQ  64           // [64]
#define WS_ATT  16384        // [64*4096] f32
// ws byte offsets for f16 regions (each 512 KB)
#define QT_B 1310720
#define KT_B 1835008
#define VB_B 2359296

typedef _Float16 h4_t __attribute__((ext_vector_type(4)));
typedef __fp16   fp16v2 __attribute__((ext_vector_type(2)));
typedef float    f4_t  __attribute__((ext_vector_type(4)));

union H4 { h4_t h; int2 v; int i[2]; };

static __device__ __forceinline__ int pkrtz(float a, float b) {
    fp16v2 p = __builtin_amdgcn_cvt_pkrtz(a, b);
    union { fp16v2 h; int i; } u; u.h = p; return u.i;
}

// ---------------- GroupNorm stage 1: per-channel partial sums ----------------
__global__ __launch_bounds__(256) void k_gnstat1(const float* __restrict__ x,
                                                 float* __restrict__ ws) {
    int b = blockIdx.x;
    int tid = threadIdx.x;
    const float4* p = (const float4*)(x + b * 4096);
    float s = 0.f, sq = 0.f;
    #pragma unroll
    for (int i = 0; i < 4; ++i) {
        float4 v = p[tid + i * 256];
        s  += v.x + v.y + v.z + v.w;
        sq += v.x * v.x + v.y * v.y + v.z * v.z + v.w * v.w;
    }
    #pragma unroll
    for (int m = 32; m >= 1; m >>= 1) {
        s  += __shfl_xor(s, m);
        sq += __shfl_xor(sq, m);
    }
    __shared__ float ls[4], lq[4];
    int w = tid >> 6;
    if ((tid & 63) == 0) { ls[w] = s; lq[w] = sq; }
    __syncthreads();
    if (tid == 0) {
        ws[WS_PSUM + b] = ls[0] + ls[1] + ls[2] + ls[3];
        ws[WS_PSQ  + b] = lq[0] + lq[1] + lq[2] + lq[3];
    }
}

// ---------------- QKV projection (GN fold fused), writes f16 MFMA layouts ----------------
// grid (16, 24), block 256: s-tile 256 (1 s/thread), o-tile 8 (one head-slice)
__global__ __launch_bounds__(256) void k_qkv(const float* __restrict__ x,
                                             const float* __restrict__ qkvw,
                                             const float* __restrict__ gnw,
                                             const float* __restrict__ gnb,
                                             float* __restrict__ ws) {
    __shared__ float la[64], lb2[64], lw[512], lbias[8];
    int tid = threadIdx.x;
    int o0 = blockIdx.y * 8;
    int s = blockIdx.x * 256 + tid;

    if (tid < 64) {                 // finalize GN stats (redundant per block, cheap)
        float sm = ws[WS_PSUM + tid];
        float sq = ws[WS_PSQ + tid];
        #pragma unroll
        for (int m = 1; m < 8; m <<= 1) {
            sm += __shfl_xor(sm, m);
            sq += __shfl_xor(sq, m);
        }
        const float inv_n = 1.0f / 32768.0f;
        float mu  = sm * inv_n;
        float var = sq * inv_n - mu * mu;
        float rs  = rsqrtf(var + EPS);
        float a   = rs * gnw[tid];
        la[tid]  = a;
        lb2[tid] = gnb[tid] - mu * a;
    }
    __syncthreads();
    lw[tid]       = qkvw[o0 * 64 + tid]       * la[tid & 63];
    lw[tid + 256] = qkvw[o0 * 64 + 256 + tid] * la[tid & 63];
    {
        int wv = tid >> 6, ln = tid & 63;
        #pragma unroll
        for (int j = 0; j < 2; ++j) {
            int o = wv * 2 + j;
            float pb = qkvw[(o0 + o) * 64 + ln] * lb2[ln];
            #pragma unroll
            for (int m = 1; m < 64; m <<= 1) pb += __shfl_xor(pb, m);
            if (ln == 0) lbias[o] = pb;
        }
    }
    __syncthreads();

    float acc[8];
    #pragma unroll
    for (int o = 0; o < 8; ++o) acc[o] = lbias[o];
    for (int c = 0; c < 64; ++c) {
        float xv = x[c * S + s];
        #pragma unroll
        for (int o = 0; o < 8; ++o) acc[o] = fmaf(lw[o * 64 + c], xv, acc[o]);
    }

    char* base = (char*)ws;
    if (o0 < 64) {                       // Q -> Qt[h][s][d], pre-scaled by 8^-0.5*log2(e)
        const float qsc = 0.51006776f;
        int hh = o0 >> 3;
        int4 r;
        r.x = pkrtz(acc[0] * qsc, acc[1] * qsc);
        r.y = pkrtz(acc[2] * qsc, acc[3] * qsc);
        r.z = pkrtz(acc[4] * qsc, acc[5] * qsc);
        r.w = pkrtz(acc[6] * qsc, acc[7] * qsc);
        *(int4*)(base + QT_B + (size_t)(hh * 4096 + s) * 16) = r;
    } else if (o0 < 128) {               // K -> Kt[h][t][d]
        int hh = (o0 - 64) >> 3;
        int4 r;
        r.x = pkrtz(acc[0], acc[1]);
        r.y = pkrtz(acc[2], acc[3]);
        r.z = pkrtz(acc[4], acc[5]);
        r.w = pkrtz(acc[6], acc[7]);
        *(int4*)(base + KT_B + (size_t)(hh * 4096 + s) * 16) = r;
    } else {                             // V -> Vb[h][d][t]
        int hh = (o0 - 128) >> 3;
        _Float16* vb = (_Float16*)(base + VB_B);
        #pragma unroll
        for (int d = 0; d < 8; ++d)
            vb[(size_t)((hh * 8 + d) * 4096) + s] = (_Float16)acc[d];
    }
}

// ---------------- Attention via 16x16x16 f16 MFMA, register-resident P ------
// grid (128, 8), block 512: 32 queries/block, 8 waves = 8 t-chunks of 512.
// Key identity: for 16x16x16, C/D layout (col=lane&15, row=quad*4+reg) ==
// B-operand layout (n=lane&15, k=quad*4+reg). So S^T = K·Q (A=K[t][d],
// B=Q[s][d]) exits the QK MFMA already in PV's B-operand layout:
// exp2+pkrtz in registers, feed PV: A=(V^T|ones) rows d (d==8 row of ones
// makes acc row 8 the softmax denominator). NO LDS in the K-loop.
__global__ __launch_bounds__(512, 8) void k_attn(float* __restrict__ ws) {
    const int h = blockIdx.y;
    const int q0 = blockIdx.x * 32;
    const int tid = threadIdx.x;
    const int w = tid >> 6;          // 0..7 t-chunk
    const int lane = tid & 63;
    const int col = lane & 15;
    const int quad = lane >> 4;

    const char* base = (const char*)ws;
    const _Float16* Qt = (const _Float16*)(base + QT_B) + (size_t)h * 4096 * 8;
    const _Float16* Kt = (const _Float16*)(base + KT_B) + (size_t)h * 4096 * 8;
    const _Float16* Vb = (const _Float16*)(base + VB_B) + (size_t)h * 8 * 4096;

    __shared__ f4_t red[7][2][64];

    // Q B-frags: Q[s=col (+16)][d=quad*4..+3]; quads 2,3 zero (d=8..15 pad)
    H4 q0f, q1f;
    q0f.i[0] = q0f.i[1] = 0;
    q1f = q0f;
    if (quad < 2) {
        q0f.v = *(const int2*)(Qt + (size_t)(q0 + col) * 8 + quad * 4);
        q1f.v = *(const int2*)(Qt + (size_t)(q0 + 16 + col) * 8 + quad * 4);
    }

    // K A-frag: K[t=col][d=quad*4..+3]; quads 2,3 zero
    H4 kf;
    kf.i[0] = kf.i[1] = 0;
    // V A-frag: rows m=d=col: d<8 data (reloaded per iter), d==8 ones, else 0
    H4 vf;
    {
        int c8 = (col == 8) ? 0x3C003C00 : 0;
        vf.i[0] = c8; vf.i[1] = c8;
    }

    f4_t acc0 = {0.f, 0.f, 0.f, 0.f};
    f4_t acc1 = {0.f, 0.f, 0.f, 0.f};
    const f4_t z = {0.f, 0.f, 0.f, 0.f};

    const int tbase = w * 512;
    #pragma unroll 2
    for (int it = 0; it < 32; ++it) {
        const int tt = tbase + it * 16;
        if (quad < 2)
            kf.v = *(const int2*)(Kt + (size_t)(tt + col) * 8 + quad * 4);
        if (col < 8)
            vf.v = *(const int2*)(Vb + (size_t)col * 4096 + tt + quad * 4);

        f4_t s0 = __builtin_amdgcn_mfma_f32_16x16x16f16(kf.h, q0f.h, z, 0, 0, 0);
        f4_t s1 = __builtin_amdgcn_mfma_f32_16x16x16f16(kf.h, q1f.h, z, 0, 0, 0);

        H4 p0, p1;
        p0.i[0] = pkrtz(EXP2F(s0[0]), EXP2F(s0[1]));
        p0.i[1] = pkrtz(EXP2F(s0[2]), EXP2F(s0[3]));
        p1.i[0] = pkrtz(EXP2F(s1[0]), EXP2F(s1[1]));
        p1.i[1] = pkrtz(EXP2F(s1[2]), EXP2F(s1[3]));

        acc0 = __builtin_amdgcn_mfma_f32_16x16x16f16(vf.h, p0.h, acc0, 0, 0, 0);
        acc1 = __builtin_amdgcn_mfma_f32_16x16x16f16(vf.h, p1.h, acc1, 0, 0, 0);
    }

    if (w > 0) { red[w - 1][0][lane] = acc0; red[w - 1][1][lane] = acc1; }
    __syncthreads();
    if (w == 0) {
        #pragma unroll
        for (int r = 0; r < 7; ++r) {
            acc0 += red[r][0][lane];
            acc1 += red[r][1][lane];
        }
        float inv0 = 1.0f / __shfl(acc0[0], 32 + col, 64);  // row d=8 = denom
        float inv1 = 1.0f / __shfl(acc1[0], 32 + col, 64);
        if (quad < 2) {
            float* att = ws + WS_ATT + (size_t)(h * 8 + quad * 4) * S + q0;
            #pragma unroll
            for (int r = 0; r < 4; ++r) {
                att[r * S + col]      = acc0[r] * inv0;
                att[r * S + 16 + col] = acc1[r] * inv1;
            }
        }
    }
}

// ---------------- Out projection + bias + residual ----------------
// grid (16, 8), block 256: s-tile 256 (1 s/thread), o-tile 8
__global__ __launch_bounds__(256) void k_out(const float* __restrict__ x,
                                             const float* __restrict__ outw,
                                             const float* __restrict__ outb,
                                             const float* __restrict__ ws,
                                             float* __restrict__ out) {
    __shared__ float lw[512];
    __shared__ float lb[8];
    int tid = threadIdx.x;
    int o0 = blockIdx.y * 8;
    int s = blockIdx.x * 256 + tid;
    lw[tid]       = outw[o0 * 64 + tid];
    lw[tid + 256] = outw[o0 * 64 + 256 + tid];
    if (tid < 8) lb[tid] = outb[o0 + tid];
    __syncthreads();

    float acc[8];
    #pragma unroll
    for (int o = 0; o < 8; ++o) acc[o] = lb[o];
    const float* att = ws + WS_ATT;
    for (int c = 0; c < 64; ++c) {
        float av = att[c * S + s];
        #pragma unroll
        for (int o = 0; o < 8; ++o) acc[o] = fmaf(lw[o * 64 + c], av, acc[o]);
    }
    #pragma unroll
    for (int o = 0; o < 8; ++o)
        out[(o0 + o) * S + s] = acc[o] + x[(o0 + o) * S + s];
}

extern "C" void kernel_launch(void* const* d_in, const int* in_sizes, int n_in,
                              void* d_out, int out_size, void* d_ws, size_t ws_size,
                              hipStream_t stream) {
    const float* x    = (const float*)d_in[0];
    const float* gnw  = (const float*)d_in[1];
    const float* gnb  = (const float*)d_in[2];
    const float* qkvw = (const float*)d_in[3];
    const float* outw = (const float*)d_in[4];
    const float* outb = (const float*)d_in[5];
    float* out = (float*)d_out;
    float* ws  = (float*)d_ws;

    hipLaunchKernelGGL(k_gnstat1, dim3(64), dim3(256), 0, stream, x, ws);
    hipLaunchKernelGGL(k_qkv, dim3(16, 24), dim3(256), 0, stream, x, qkvw, gnw, gnb, ws);
    hipLaunchKernelGGL(k_attn, dim3(128, 8), dim3(512), 0, stream, ws);
    hipLaunchKernelGGL(k_out, dim3(16, 8), dim3(256), 0, stream, x, outw, outb, ws, out);
}

// Round 7
// 92.396 us; speedup vs baseline: 1.1877x; 1.1877x over previous
//
#include <hip/hip_runtime.h>
#include <math.h>

#define S 4096
#define EPS 1e-5f

#if __has_builtin(__builtin_amdgcn_exp2f)
#define EXP2F(x) __builtin_amdgcn_exp2f(x)
#else
#define EXP2F(x) exp2f(x)
#endif

// ws float-index offsets
#define WS_PSUM 0            // [64]
#define WS_PSQ  64           // [64]
#define WS_ATT  16384        // [64*4096] f32
// ws byte offsets for f16 regions (each 512 KB)
#define QT_B 1310720
#define KT_B 1835008
#define VB_B 2359296

typedef _Float16 h8_t __attribute__((ext_vector_type(8)));
typedef __fp16   fp16v2 __attribute__((ext_vector_type(2)));
typedef float    f4_t  __attribute__((ext_vector_type(4)));
typedef float    f16_t __attribute__((ext_vector_type(16)));

union H8 { h8_t h; int4 v; int i[4]; };

static __device__ __forceinline__ int pkrtz(float a, float b) {
    fp16v2 p = __builtin_amdgcn_cvt_pkrtz(a, b);
    union { fp16v2 h; int i; } u; u.h = p; return u.i;
}

// ---------------- GroupNorm stage 1: per-channel partial sums ----------------
__global__ __launch_bounds__(256) void k_gnstat1(const float* __restrict__ x,
                                                 float* __restrict__ ws) {
    int b = blockIdx.x;
    int tid = threadIdx.x;
    const float4* p = (const float4*)(x + b * 4096);
    float s = 0.f, sq = 0.f;
    #pragma unroll
    for (int i = 0; i < 4; ++i) {
        float4 v = p[tid + i * 256];
        s  += v.x + v.y + v.z + v.w;
        sq += v.x * v.x + v.y * v.y + v.z * v.z + v.w * v.w;
    }
    #pragma unroll
    for (int m = 32; m >= 1; m >>= 1) {
        s  += __shfl_xor(s, m);
        sq += __shfl_xor(sq, m);
    }
    __shared__ float ls[4], lq[4];
    int w = tid >> 6;
    if ((tid & 63) == 0) { ls[w] = s; lq[w] = sq; }
    __syncthreads();
    if (tid == 0) {
        ws[WS_PSUM + b] = ls[0] + ls[1] + ls[2] + ls[3];
        ws[WS_PSQ  + b] = lq[0] + lq[1] + lq[2] + lq[3];
    }
}

// ---------------- QKV projection (GN fold fused), writes f16 MFMA layouts ----------------
// grid (16, 48), block 256: s-tile 256 (1 s/thread), o-tile 4 (half head-slice)
__global__ __launch_bounds__(256) void k_qkv(const float* __restrict__ x,
                                             const float* __restrict__ qkvw,
                                             const float* __restrict__ gnw,
                                             const float* __restrict__ gnb,
                                             float* __restrict__ ws) {
    __shared__ float la[64], lb2[64], lw[256], lbias[4];
    int tid = threadIdx.x;
    int o0 = blockIdx.y * 4;
    int s = blockIdx.x * 256 + tid;

    if (tid < 64) {                 // finalize GN stats (redundant per block, cheap)
        float sm = ws[WS_PSUM + tid];
        float sq = ws[WS_PSQ + tid];
        #pragma unroll
        for (int m = 1; m < 8; m <<= 1) {
            sm += __shfl_xor(sm, m);
            sq += __shfl_xor(sq, m);
        }
        const float inv_n = 1.0f / 32768.0f;
        float mu  = sm * inv_n;
        float var = sq * inv_n - mu * mu;
        float rs  = rsqrtf(var + EPS);
        float a   = rs * gnw[tid];
        la[tid]  = a;
        lb2[tid] = gnb[tid] - mu * a;
    }
    __syncthreads();
    lw[tid] = qkvw[o0 * 64 + tid] * la[tid & 63];
    {
        int wv = tid >> 6, ln = tid & 63;   // wave wv handles o = o0+wv
        float pb = qkvw[(o0 + wv) * 64 + ln] * lb2[ln];
        #pragma unroll
        for (int m = 1; m < 64; m <<= 1) pb += __shfl_xor(pb, m);
        if (ln == 0) lbias[wv] = pb;
    }
    __syncthreads();

    float acc[4];
    #pragma unroll
    for (int o = 0; o < 4; ++o) acc[o] = lbias[o];
    for (int c = 0; c < 64; ++c) {
        float xv = x[c * S + s];
        #pragma unroll
        for (int o = 0; o < 4; ++o) acc[o] = fmaf(lw[o * 64 + c], xv, acc[o]);
    }

    char* base = (char*)ws;
    if (o0 < 64) {                       // Q -> Qt[h][s][d], pre-scaled by 8^-0.5*log2(e)
        const float qsc = 0.51006776f;
        int hh = o0 >> 3, db = o0 & 7;   // db in {0,4}
        int2 r;
        r.x = pkrtz(acc[0] * qsc, acc[1] * qsc);
        r.y = pkrtz(acc[2] * qsc, acc[3] * qsc);
        *(int2*)(base + QT_B + (size_t)(hh * 4096 + s) * 16 + db * 2) = r;
    } else if (o0 < 128) {               // K -> Kt[h][t][d]
        int hh = (o0 - 64) >> 3, db = o0 & 7;
        int2 r;
        r.x = pkrtz(acc[0], acc[1]);
        r.y = pkrtz(acc[2], acc[3]);
        *(int2*)(base + KT_B + (size_t)(hh * 4096 + s) * 16 + db * 2) = r;
    } else {                             // V -> Vb[h][d][t]
        int hh = (o0 - 128) >> 3, db = o0 & 7;
        _Float16* vb = (_Float16*)(base + VB_B);
        #pragma unroll
        for (int d = 0; d < 4; ++d)
            vb[(size_t)((hh * 8 + db + d) * 4096) + s] = (_Float16)acc[d];
    }
}

// ---------------- Attention via f16 MFMA (R5 structure, K-only prefetch) ----
// grid (128, 8), block 512: 32 queries/block, 8 waves = 8 t-chunks of 512.
// QK: ONE 32x32x16 MFMA (A=K rows t, B=Q cols s; d=8 real, upper-half lanes
// zero). C-layout: col=lane&31 (s), t=(reg&3)+8*(reg>>2)+4*(lane>>5).
// exp2 in-place; per b one ds_write_b64 to P[s][t] (stride 40 halves).
// PV: 2x 16x16x32 with (V|ones) A-frag so acc row d=8 = softmax denominator.
// V loaded at iter top (slack until PV at bottom); K prefetched one iter.
__global__ __launch_bounds__(512, 8) void k_attn(float* __restrict__ ws) {
    const int h = blockIdx.y;
    const int q0 = blockIdx.x * 32;
    const int tid = threadIdx.x;
    const int w = tid >> 6;          // 0..7 t-chunk
    const int lane = tid & 63;
    const int col16 = lane & 15;
    const int quad = lane >> 4;
    const int col32 = lane & 31;
    const int half = lane >> 5;

    const char* base = (const char*)ws;
    const _Float16* Qt = (const _Float16*)(base + QT_B) + (size_t)h * 4096 * 8;
    const _Float16* Kt = (const _Float16*)(base + KT_B) + (size_t)h * 4096 * 8;
    const _Float16* Vb = (const _Float16*)(base + VB_B) + (size_t)h * 8 * 4096;

    __shared__ _Float16 Plds[8][32][40];   // per-wave 32s x 32t tile, +8 pad
    __shared__ f4_t red[7][2][64];

    // Q B-frag (32x32x16): lane<32 holds Q[s=col32][d=0..7]; upper half zero
    H8 qf;
    qf.i[0] = qf.i[1] = qf.i[2] = qf.i[3] = 0;
    if (half == 0) qf.v = *(const int4*)(Qt + (size_t)(q0 + col32) * 8);

    // K A-frag: lane<32 holds K[t=col32][d=0..7]; upper half stays zero
    H8 kf;
    kf.i[0] = kf.i[1] = kf.i[2] = kf.i[3] = 0;
    // V A-frag (16x16x32): rows m=d: d<8 data (loaded per iter), d==8 ones, else 0
    H8 vf;
    {
        int c8 = (col16 == 8) ? 0x3C003C00 : 0;
        vf.i[0] = c8; vf.i[1] = c8; vf.i[2] = c8; vf.i[3] = c8;
    }

    const int tbase = w * 512;
    if (half == 0) kf.v = *(const int4*)(Kt + (size_t)(tbase + col32) * 8);

    f4_t acc0 = {0.f, 0.f, 0.f, 0.f};
    f4_t acc1 = {0.f, 0.f, 0.f, 0.f};
    f16_t zc = {0.f, 0.f, 0.f, 0.f, 0.f, 0.f, 0.f, 0.f,
                0.f, 0.f, 0.f, 0.f, 0.f, 0.f, 0.f, 0.f};
    _Float16* Pw = &Plds[w][0][0];

    for (int it = 0; it < 16; ++it) {
        const int tt = tbase + it * 32;
        // V for THIS iter: consumer (PV) is after exp+LDS round-trip -> slack
        if (col16 < 8)
            vf.v = *(const int4*)(Vb + (size_t)col16 * 4096 + tt + quad * 8);

        f16_t sc = __builtin_amdgcn_mfma_f32_32x32x16_f16(kf.h, qf.h, zc, 0, 0, 0);

        // prefetch next K tile (reads past-end junk at it=15 stay inside ws)
        H8 nk = kf;                      // keeps upper-half zeros
        if (half == 0)
            nk.v = *(const int4*)(Kt + (size_t)(tt + 32 + col32) * 8);

        #pragma unroll
        for (int r = 0; r < 16; ++r) sc[r] = EXP2F(sc[r]);

        // b=reg>>2: t = 8b + 4*half + {0..3}, s=col32 -> one b64 per b
        #pragma unroll
        for (int b = 0; b < 4; ++b) {
            int2 wv = { pkrtz(sc[4 * b], sc[4 * b + 1]),
                        pkrtz(sc[4 * b + 2], sc[4 * b + 3]) };
            *(int2*)(Pw + col32 * 40 + 8 * b + 4 * half) = wv;
        }

        // B-frag reads: lane(quad,col16) takes P[s][t=quad*8..+7]
        H8 p0, p1;
        p0.v = *(const int4*)(Pw + col16 * 40 + quad * 8);
        p1.v = *(const int4*)(Pw + (col16 + 16) * 40 + quad * 8);

        acc0 = __builtin_amdgcn_mfma_f32_16x16x32_f16(vf.h, p0.h, acc0, 0, 0, 0);
        acc1 = __builtin_amdgcn_mfma_f32_16x16x32_f16(vf.h, p1.h, acc1, 0, 0, 0);

        kf = nk;
    }

    if (w > 0) { red[w - 1][0][lane] = acc0; red[w - 1][1][lane] = acc1; }
    __syncthreads();
    if (w == 0) {
        #pragma unroll
        for (int r = 0; r < 7; ++r) {
            acc0 += red[r][0][lane];
            acc1 += red[r][1][lane];
        }
        float inv0 = 1.0f / __shfl(acc0[0], 32 + col16, 64);  // row d=8 = denom
        float inv1 = 1.0f / __shfl(acc1[0], 32 + col16, 64);
        if (quad < 2) {
            float* att = ws + WS_ATT + (size_t)(h * 8 + quad * 4) * S + q0;
            #pragma unroll
            for (int r = 0; r < 4; ++r) {
                att[r * S + col16]      = acc0[r] * inv0;
                att[r * S + 16 + col16] = acc1[r] * inv1;
            }
        }
    }
}

// ---------------- Out projection + bias + residual ----------------
// grid (16, 64), block 256: s-tile 256 (1 s/thread), o-tile 1 -> 1024 blocks,
// 4 waves/SIMD (was 0.5 at o-tile 8 — k_out was the occupancy floor).
__global__ __launch_bounds__(256) void k_out(const float* __restrict__ x,
                                             const float* __restrict__ outw,
                                             const float* __restrict__ outb,
                                             const float* __restrict__ ws,
                                             float* __restrict__ out) {
    __shared__ float lw[64];
    int tid = threadIdx.x;
    int o = blockIdx.y;
    int s = blockIdx.x * 256 + tid;
    if (tid < 64) lw[tid] = outw[o * 64 + tid];
    __syncthreads();

    float acc = outb[o];
    const float* att = ws + WS_ATT;
    for (int c = 0; c < 64; ++c)
        acc = fmaf(lw[c], att[c * S + s], acc);
    out[o * S + s] = acc + x[o * S + s];
}

extern "C" void kernel_launch(void* const* d_in, const int* in_sizes, int n_in,
                              void* d_out, int out_size, void* d_ws, size_t ws_size,
                              hipStream_t stream) {
    const float* x    = (const float*)d_in[0];
    const float* gnw  = (const float*)d_in[1];
    const float* gnb  = (const float*)d_in[2];
    const float* qkvw = (const float*)d_in[3];
    const float* outw = (const float*)d_in[4];
    const float* outb = (const float*)d_in[5];
    float* out = (float*)d_out;
    float* ws  = (float*)d_ws;

    hipLaunchKernelGGL(k_gnstat1, dim3(64), dim3(256), 0, stream, x, ws);
    hipLaunchKernelGGL(k_qkv, dim3(16, 48), dim3(256), 0, stream, x, qkvw, gnw, gnb, ws);
    hipLaunchKernelGGL(k_attn, dim3(128, 8), dim3(512), 0, stream, ws);
    hipLaunchKernelGGL(k_out, dim3(16, 64), dim3(256), 0, stream, x, outw, outb, ws, out);
}